// Round 1
// baseline (6986.414 us; speedup 1.0000x reference)
//
#include <hip/hip_runtime.h>
#include <cstdint>
#include <cstddef>

// SAGE with LSTM aggregator, 2 layers. N=50000, D=16, IN=HID=128, OUT=64.
// R1: fp32 VALU baseline. Structure: weight-transpose prep -> per-layer
// [lstm_agg (gather fused) -> out_linear]. Compute-bound; fp32 roofline ~2.7ms.

constexpr int IN   = 128;   // feature dim layer1 (and hidden size of both LSTMs)
constexpr int DEG  = 16;    // neighbors per node
constexpr int G4   = 512;   // 4*128 gates

__device__ __forceinline__ float fsigmoid(float x) {
    float e = __expf(-x);
    return __builtin_amdgcn_rcpf(1.0f + e);
}
__device__ __forceinline__ float ftanh(float x) {
    // tanh(x) = 2*sigmoid(2x) - 1 = 2/(1+exp(-2x)) - 1
    float e = __expf(-2.0f * x);
    return __fmaf_rn(2.0f, __builtin_amdgcn_rcpf(1.0f + e), -1.0f);
}

// dst[C][R] = src[R][C] transpose
__global__ void k_transpose(const float* __restrict__ src, float* __restrict__ dst,
                            int R, int C) {
    int i = blockIdx.x * blockDim.x + threadIdx.x;
    if (i < R * C) {
        int r = i / C, c = i - r * C;
        dst[c * R + r] = src[i];
    }
}

__global__ void k_bias_sum(const float* __restrict__ a, const float* __restrict__ b,
                           float* __restrict__ o, int n) {
    int i = blockIdx.x * blockDim.x + threadIdx.x;
    if (i < n) o[i] = a[i] + b[i];
}

// One block = 32 nodes. 256 threads: j = tid&127 (gate column), slot = tid>>7
// (2 slots x 16 nodes). Per step: stage gathered x_t in LDS, compute 4 gate
// accumulators per (node,j) over K=128 (x part) + 128 (h part), elementwise
// LSTM update with c in registers, h kept in LDS.
__global__ __launch_bounds__(256) void k_lstm_agg(
    const float* __restrict__ feats,   // [N,128] gather source
    const int*   __restrict__ nbr,     // [N,16]
    const float* __restrict__ wT_ih,   // [128][512]  (k-major)
    const float* __restrict__ wT_hh,   // [128][512]
    const float* __restrict__ bsum,    // [512] b_ih+b_hh
    float*       __restrict__ h_out,   // [N,128]
    int N)
{
    __shared__ alignas(16) float x_lds[32][IN];
    __shared__ alignas(16) float h_lds[32][IN];
    __shared__ int idx[32][DEG];

    const int tid  = threadIdx.x;
    const int j    = tid & 127;
    const int slot = tid >> 7;          // 0..1
    const int node0 = blockIdx.x * 32;

    for (int i = tid; i < 32 * DEG; i += 256) {
        int n = i >> 4, t = i & 15;
        int gn = node0 + n;
        idx[n][t] = (gn < N) ? nbr[gn * DEG + t] : 0;
    }
    for (int i = tid; i < 32 * IN; i += 256) (&h_lds[0][0])[i] = 0.0f;

    float c[16];
#pragma unroll
    for (int n = 0; n < 16; ++n) c[n] = 0.0f;

    const float bi = bsum[j];
    const float bf = bsum[128 + j];
    const float bg = bsum[256 + j];
    const float bo = bsum[384 + j];

    __syncthreads();

    for (int t = 0; t < DEG; ++t) {
        // stage x_t = feats[nbr[node, t], :] -> x_lds (coalesced float4)
        for (int i = tid; i < 32 * (IN / 4); i += 256) {
            int n = i >> 5, c4 = i & 31;
            const float4* src = (const float4*)(feats + (size_t)idx[n][t] * IN);
            ((float4*)&x_lds[n][0])[c4] = src[c4];
        }
        __syncthreads();   // x_lds ready; previous-step h_lds writes visible

        float ai[16], af[16], ag[16], ao[16];
#pragma unroll
        for (int n = 0; n < 16; ++n) { ai[n] = bi; af[n] = bf; ag[n] = bg; ao[n] = bo; }

#pragma unroll 2
        for (int k = 0; k < IN; ++k) {
            // 8 coalesced weight streams (L2-resident: 512KB working set/block/step)
            const float wii = wT_ih[k * G4 +       j];
            const float wif = wT_ih[k * G4 + 128 + j];
            const float wig = wT_ih[k * G4 + 256 + j];
            const float wio = wT_ih[k * G4 + 384 + j];
            const float whi = wT_hh[k * G4 +       j];
            const float whf = wT_hh[k * G4 + 128 + j];
            const float whg = wT_hh[k * G4 + 256 + j];
            const float who = wT_hh[k * G4 + 384 + j];
#pragma unroll
            for (int n = 0; n < 16; ++n) {
                float xv = x_lds[slot * 16 + n][k];   // wave-uniform -> LDS broadcast
                float hv = h_lds[slot * 16 + n][k];
                ai[n] = __fmaf_rn(xv, wii, __fmaf_rn(hv, whi, ai[n]));
                af[n] = __fmaf_rn(xv, wif, __fmaf_rn(hv, whf, af[n]));
                ag[n] = __fmaf_rn(xv, wig, __fmaf_rn(hv, whg, ag[n]));
                ao[n] = __fmaf_rn(xv, wio, __fmaf_rn(hv, who, ao[n]));
            }
        }
        __syncthreads();   // everyone done reading h_lds/x_lds

        // elementwise LSTM update (PyTorch gate order i,f,g,o)
#pragma unroll
        for (int n = 0; n < 16; ++n) {
            float iv = fsigmoid(ai[n]);
            float fv = fsigmoid(af[n]);
            float gv = ftanh(ag[n]);
            float ov = fsigmoid(ao[n]);
            c[n] = __fmaf_rn(fv, c[n], iv * gv);
            h_lds[slot * 16 + n][j] = ov * ftanh(c[n]);
        }
        // no barrier needed here: next x_t staging touches a different buffer;
        // the barrier after staging makes these h writes visible before reads.
    }

    // final h (this thread wrote these LDS slots itself)
#pragma unroll
    for (int n = 0; n < 16; ++n) {
        int gn = node0 + slot * 16 + n;
        if (gn < N) h_out[(size_t)gn * IN + j] = h_lds[slot * 16 + n][j];
    }
}

// out[n,j] = act( sum_k x[n,k]*wTs[k,j] + sum_k h[n,k]*wTn[k,j] + bias[j] )
// ACT: 0 = relu, 1 = sigmoid
template <int NOUT, int ACT>
__global__ __launch_bounds__(256) void k_out_linear(
    const float* __restrict__ x,     // [N,128]
    const float* __restrict__ h,     // [N,128]
    const float* __restrict__ wTs,   // [128][NOUT]
    const float* __restrict__ wTn,   // [128][NOUT]
    const float* __restrict__ bias,  // [NOUT]
    float*       __restrict__ out,   // [N,NOUT]
    int N)
{
    constexpr int SLOTS = 256 / NOUT;
    constexpr int NPS   = 32 / SLOTS;
    __shared__ alignas(16) float x_lds[32][IN];
    __shared__ alignas(16) float h_lds[32][IN];

    const int tid  = threadIdx.x;
    const int j    = tid % NOUT;
    const int slot = tid / NOUT;
    const int node0 = blockIdx.x * 32;

    for (int i = tid; i < 32 * (IN / 4); i += 256) {
        int n = i >> 5, c4 = i & 31;
        int gn = node0 + n; if (gn >= N) gn = N - 1;
        ((float4*)&x_lds[n][0])[c4] = ((const float4*)(x + (size_t)gn * IN))[c4];
        ((float4*)&h_lds[n][0])[c4] = ((const float4*)(h + (size_t)gn * IN))[c4];
    }
    __syncthreads();

    float acc[NPS];
    const float bj = bias[j];
#pragma unroll
    for (int n = 0; n < NPS; ++n) acc[n] = bj;

#pragma unroll 2
    for (int k = 0; k < IN; ++k) {
        const float ws = wTs[k * NOUT + j];
        const float wn = wTn[k * NOUT + j];
#pragma unroll
        for (int n = 0; n < NPS; ++n) {
            acc[n] = __fmaf_rn(x_lds[slot * NPS + n][k], ws,
                     __fmaf_rn(h_lds[slot * NPS + n][k], wn, acc[n]));
        }
    }

#pragma unroll
    for (int n = 0; n < NPS; ++n) {
        int gn = node0 + slot * NPS + n;
        if (gn < N) {
            float v = acc[n];
            v = (ACT == 0) ? fmaxf(v, 0.0f) : fsigmoid(v);
            out[(size_t)gn * NOUT + j] = v;
        }
    }
}

extern "C" void kernel_launch(void* const* d_in, const int* in_sizes, int n_in,
                              void* d_out, int out_size, void* d_ws, size_t ws_size,
                              hipStream_t stream)
{
    const float* feats    = (const float*)d_in[0];
    const int*   nbr      = (const int*)  d_in[1];
    const float* w_ih1    = (const float*)d_in[2];
    const float* w_hh1    = (const float*)d_in[3];
    const float* b_ih1    = (const float*)d_in[4];
    const float* b_hh1    = (const float*)d_in[5];
    const float* w_self1  = (const float*)d_in[6];
    const float* w_neigh1 = (const float*)d_in[7];
    const float* b1       = (const float*)d_in[8];
    const float* w_ih2    = (const float*)d_in[9];
    const float* w_hh2    = (const float*)d_in[10];
    const float* b_ih2    = (const float*)d_in[11];
    const float* b_hh2    = (const float*)d_in[12];
    const float* w_self2  = (const float*)d_in[13];
    const float* w_neigh2 = (const float*)d_in[14];
    const float* b2       = (const float*)d_in[15];
    float* out = (float*)d_out;

    const int N = in_sizes[0] / IN;   // 50000

    char* ws = (char*)d_ws;
    size_t off = 0;
    auto alloc = [&](size_t bytes) -> float* {
        float* p = (float*)(ws + off);
        off += (bytes + 255) & ~(size_t)255;
        return p;
    };
    float* wT_ih1    = alloc(512 * 128 * 4);
    float* wT_hh1    = alloc(512 * 128 * 4);
    float* wT_ih2    = alloc(512 * 128 * 4);
    float* wT_hh2    = alloc(512 * 128 * 4);
    float* wT_self1  = alloc(128 * 128 * 4);
    float* wT_neigh1 = alloc(128 * 128 * 4);
    float* wT_self2  = alloc(64 * 128 * 4);
    float* wT_neigh2 = alloc(64 * 128 * 4);
    float* bsum1     = alloc(512 * 4);
    float* bsum2     = alloc(512 * 4);
    float* h_buf     = alloc((size_t)N * 128 * 4);   // h_neigh (reused both layers)
    float* out1      = alloc((size_t)N * 128 * 4);   // relu(layer1) = layer2 features

    // ---- prep: transposes + bias sums (recomputed every call; ws is re-poisoned)
    k_transpose<<<dim3((512 * 128 + 255) / 256), dim3(256), 0, stream>>>(w_ih1, wT_ih1, 512, 128);
    k_transpose<<<dim3((512 * 128 + 255) / 256), dim3(256), 0, stream>>>(w_hh1, wT_hh1, 512, 128);
    k_transpose<<<dim3((512 * 128 + 255) / 256), dim3(256), 0, stream>>>(w_ih2, wT_ih2, 512, 128);
    k_transpose<<<dim3((512 * 128 + 255) / 256), dim3(256), 0, stream>>>(w_hh2, wT_hh2, 512, 128);
    k_transpose<<<dim3((128 * 128 + 255) / 256), dim3(256), 0, stream>>>(w_self1, wT_self1, 128, 128);
    k_transpose<<<dim3((128 * 128 + 255) / 256), dim3(256), 0, stream>>>(w_neigh1, wT_neigh1, 128, 128);
    k_transpose<<<dim3((64 * 128 + 255) / 256), dim3(256), 0, stream>>>(w_self2, wT_self2, 64, 128);
    k_transpose<<<dim3((64 * 128 + 255) / 256), dim3(256), 0, stream>>>(w_neigh2, wT_neigh2, 64, 128);
    k_bias_sum<<<dim3(2), dim3(256), 0, stream>>>(b_ih1, b_hh1, bsum1, 512);
    k_bias_sum<<<dim3(2), dim3(256), 0, stream>>>(b_ih2, b_hh2, bsum2, 512);

    const int nblk = (N + 31) / 32;

    // ---- layer 1
    k_lstm_agg<<<dim3(nblk), dim3(256), 0, stream>>>(feats, nbr, wT_ih1, wT_hh1, bsum1, h_buf, N);
    k_out_linear<128, 0><<<dim3(nblk), dim3(256), 0, stream>>>(feats, h_buf, wT_self1, wT_neigh1, b1, out1, N);

    // ---- layer 2
    k_lstm_agg<<<dim3(nblk), dim3(256), 0, stream>>>(out1, nbr, wT_ih2, wT_hh2, bsum2, h_buf, N);
    k_out_linear<64, 1><<<dim3(nblk), dim3(256), 0, stream>>>(out1, h_buf, wT_self2, wT_neigh2, b2, out, N);
}

// Round 2
// 1663.964 us; speedup vs baseline: 4.1987x; 4.1987x over previous
//
#include <hip/hip_runtime.h>
#include <cstdint>
#include <cstddef>

// SAGE-LSTM R2: gates GEMM on MFMA (v_mfma_f32_32x32x16_bf16).
// Block = 64 nodes, 4 waves; wave w owns gate cols w*32+{0,128,256,384} so the
// LSTM cell update is lane-local across i/f/g/o. Weights pre-packed to
// B-fragment order (bf16); x gathered->bf16 A-frag LDS; h round-trips LDS in
// A-frag layout via shfl_xor bf16 pairing. K=256 = [x(128) | h(128)].

constexpr int IN  = 128;
constexpr int DEG = 16;

typedef short bf16x8 __attribute__((ext_vector_type(8)));
typedef float f32x16 __attribute__((ext_vector_type(16)));

__device__ __forceinline__ float fsigmoid(float x) {
    float e = __expf(-x);
    return __builtin_amdgcn_rcpf(1.0f + e);
}
__device__ __forceinline__ float ftanh(float x) {
    float e = __expf(-2.0f * x);
    return __fmaf_rn(2.0f, __builtin_amdgcn_rcpf(1.0f + e), -1.0f);
}
__device__ __forceinline__ uint32_t pack2bf16(float a, float b) {
    uint32_t ua = __float_as_uint(a) + 0x8000u;   // round-half-up to bf16
    uint32_t ub = __float_as_uint(b) + 0x8000u;
    return (ua >> 16) | (ub & 0xFFFF0000u);
}

// ---------- prep kernels ----------

// dst[C][R] = src[R][C]
__global__ void k_transpose(const float* __restrict__ src, float* __restrict__ dst,
                            int R, int C) {
    int i = blockIdx.x * blockDim.x + threadIdx.x;
    if (i < R * C) { int r = i / C, c = i - r * C; dst[c * R + r] = src[i]; }
}

__global__ void k_bias_sum(const float* __restrict__ a, const float* __restrict__ b,
                           float* __restrict__ o, int n) {
    int i = blockIdx.x * blockDim.x + threadIdx.x;
    if (i < n) o[i] = a[i] + b[i];
}

// Pack W = [W_ih^T ; W_hh^T] (256 x 512 logical, k-major) into MFMA B-fragment
// order: flat tid = ((kst*16 + tile)*64 + lane), each thread emits its 8 bf16
// (16B). B[k][n]: n = tile*32 + (lane&31), k = kst*16 + (lane>>5)*8 + j.
__global__ void k_pack_w(const float* __restrict__ w_ih, const float* __restrict__ w_hh,
                         uint4* __restrict__ wfrag) {
    int tid  = blockIdx.x * 256 + threadIdx.x;   // 0..16383
    int lane = tid & 63;
    int tile = (tid >> 6) & 15;
    int kst  = tid >> 10;
    int n     = tile * 32 + (lane & 31);
    int kbase = kst * 16 + (lane >> 5) * 8;
    float v[8];
#pragma unroll
    for (int j = 0; j < 8; ++j) {
        int k = kbase + j;
        v[j] = (k < 128) ? w_ih[n * 128 + k] : w_hh[n * 128 + (k - 128)];
    }
    uint4 d;
    d.x = pack2bf16(v[0], v[1]);
    d.y = pack2bf16(v[2], v[3]);
    d.z = pack2bf16(v[4], v[5]);
    d.w = pack2bf16(v[6], v[7]);
    wfrag[tid] = d;
}

// ---------- LSTM aggregator (MFMA) ----------

__global__ __launch_bounds__(256, 2) void k_lstm_mfma(
    const float* __restrict__ feats,   // [N,128] gather source
    const int*   __restrict__ nbr,     // [N,16]
    const uint4* __restrict__ wfrag,   // packed B-frags, 16384 * 16B
    const float* __restrict__ bsum,    // [512] b_ih+b_hh
    float*       __restrict__ h_out,   // [N,128]
    int N)
{
    __shared__ uint4 x_frag[16 * 64];   // [kgrp 0..15][m 0..63] bf16 A-layout, 16KB
    __shared__ uint4 h_frag[16 * 64];   // same, 16KB
    __shared__ int   idxs[DEG * 64];    // [t][m], 4KB

    const int tid   = threadIdx.x;
    const int lane  = tid & 63;
    const int w     = tid >> 6;         // wave 0..3
    const int mrow  = lane & 31;
    const int khalf = lane >> 5;
    const int node0 = blockIdx.x * 64;

    // neighbor indices, clamped
    for (int i = tid; i < 64 * DEG; i += 256) {
        int m = i >> 4, t = i & 15;
        int gn = node0 + m; if (gn >= N) gn = N - 1;
        idxs[t * 64 + m] = nbr[gn * DEG + t];
    }
    // h0 = 0
    for (int i = tid; i < 16 * 64; i += 256) h_frag[i] = uint4{0u, 0u, 0u, 0u};

    float binit[4];
#pragma unroll
    for (int g = 0; g < 4; ++g) binit[g] = bsum[g * 128 + w * 32 + (lane & 31)];

    f32x16 acc[2][4];
    float  cst[2][16];
#pragma unroll
    for (int Mt = 0; Mt < 2; ++Mt)
#pragma unroll
        for (int r = 0; r < 16; ++r) {
            cst[Mt][r] = 0.0f;
#pragma unroll
            for (int g = 0; g < 4; ++g) acc[Mt][g][r] = binit[g];
        }

    const uint4* wbase = wfrag + (w * 64 + lane);   // + kst*1024 + g*256

    __syncthreads();

    const int m_st  = tid >> 2;   // staging: my node row
    const int c4_st = tid & 3;    // staging: my float4 phase

    for (int t = 0; t < DEG; ++t) {
        // ---- stage x_t: gather row, cvt to bf16, write A-frag layout.
        // 4 threads/row; per instr a 4-thread group reads 64B contiguous.
        {
            const float* src = feats + (size_t)idxs[t * 64 + m_st] * IN;
#pragma unroll
            for (int i = 0; i < 8; ++i) {
                int f4 = i * 4 + c4_st;              // float4 idx 0..31 (k=f4*4..+3)
                float4 v = ((const float4*)src)[f4];
                uint2 d;
                d.x = pack2bf16(v.x, v.y);
                d.y = pack2bf16(v.z, v.w);
                ((uint2*)&x_frag[(f4 >> 1) * 64 + m_st])[f4 & 1] = d;
            }
        }
        __syncthreads();   // x_frag(t) + h_frag(t-1) ready

        // ---- K-loop: 16 k-steps x (2 M-tiles x 4 gate-tiles) MFMA
#pragma unroll
        for (int kst = 0; kst < 16; ++kst) {
            const uint4* asrc = (kst < 8) ? &x_frag[(kst * 2 + khalf) * 64]
                                          : &h_frag[((kst - 8) * 2 + khalf) * 64];
            bf16x8 a0 = __builtin_bit_cast(bf16x8, asrc[mrow]);
            bf16x8 a1 = __builtin_bit_cast(bf16x8, asrc[32 + mrow]);
#pragma unroll
            for (int g = 0; g < 4; ++g) {
                bf16x8 b = __builtin_bit_cast(bf16x8, wbase[kst * 1024 + g * 256]);
                acc[0][g] = __builtin_amdgcn_mfma_f32_32x32x16_bf16(a0, b, acc[0][g], 0, 0, 0);
                acc[1][g] = __builtin_amdgcn_mfma_f32_32x32x16_bf16(a1, b, acc[1][g], 0, 0, 0);
            }
        }
        __syncthreads();   // all waves done reading x_frag/h_frag

        // ---- LSTM cell update (lane-local i/f/g/o), write h(t) to h_frag
#pragma unroll
        for (int Mt = 0; Mt < 2; ++Mt) {
#pragma unroll
            for (int r = 0; r < 16; ++r) {
                float gi = acc[Mt][0][r], gf = acc[Mt][1][r];
                float gg = acc[Mt][2][r], go = acc[Mt][3][r];
                acc[Mt][0][r] = binit[0];  acc[Mt][1][r] = binit[1];
                acc[Mt][2][r] = binit[2];  acc[Mt][3][r] = binit[3];
                float iv = fsigmoid(gi);
                float fv = fsigmoid(gf);
                float gv = ftanh(gg);
                float ov = fsigmoid(go);
                float cv = __fmaf_rn(fv, cst[Mt][r], iv * gv);
                cst[Mt][r] = cv;
                float hv = ov * ftanh(cv);
                // pack (j even, j odd) pairs via lane^1 exchange; even lane writes
                uint32_t hb = __float_as_uint(hv) + 0x8000u;
                uint32_t pb = (uint32_t)__shfl_xor((int)hb, 1, 64);
                if ((lane & 1) == 0) {
                    int row = Mt * 32 + (r & 3) + 8 * (r >> 2) + 4 * khalf;
                    int j   = w * 32 + (lane & 31);
                    ((uint32_t*)h_frag)[((j >> 3) * 64 + row) * 4 + ((lane >> 1) & 3)] =
                        (hb >> 16) | (pb & 0xFFFF0000u);
                }
            }
        }
        // next iter: x staging hits x_frag only; barrier after staging orders h.
    }

    __syncthreads();
    // final h: read bf16 A-layout, widen to f32, coalesced store
    for (int i = tid; i < 64 * IN; i += 256) {
        int m = i >> 7, j = i & 127;
        int gn = node0 + m;
        if (gn < N) {
            uint32_t u = ((const ushort*)h_frag)[((j >> 3) * 64 + m) * 8 + (j & 7)];
            h_out[(size_t)gn * IN + j] = __uint_as_float(u << 16);
        }
    }
}

// ---------- output linear (unchanged fp32 from R1) ----------

template <int NOUT, int ACT>
__global__ __launch_bounds__(256) void k_out_linear(
    const float* __restrict__ x, const float* __restrict__ h,
    const float* __restrict__ wTs, const float* __restrict__ wTn,
    const float* __restrict__ bias, float* __restrict__ out, int N)
{
    constexpr int SLOTS = 256 / NOUT;
    constexpr int NPS   = 32 / SLOTS;
    __shared__ alignas(16) float x_lds[32][IN];
    __shared__ alignas(16) float h_lds[32][IN];

    const int tid  = threadIdx.x;
    const int j    = tid % NOUT;
    const int slot = tid / NOUT;
    const int node0 = blockIdx.x * 32;

    for (int i = tid; i < 32 * (IN / 4); i += 256) {
        int n = i >> 5, c4 = i & 31;
        int gn = node0 + n; if (gn >= N) gn = N - 1;
        ((float4*)&x_lds[n][0])[c4] = ((const float4*)(x + (size_t)gn * IN))[c4];
        ((float4*)&h_lds[n][0])[c4] = ((const float4*)(h + (size_t)gn * IN))[c4];
    }
    __syncthreads();

    float acc[NPS];
    const float bj = bias[j];
#pragma unroll
    for (int n = 0; n < NPS; ++n) acc[n] = bj;

#pragma unroll 2
    for (int k = 0; k < IN; ++k) {
        const float ws = wTs[k * NOUT + j];
        const float wn = wTn[k * NOUT + j];
#pragma unroll
        for (int n = 0; n < NPS; ++n) {
            acc[n] = __fmaf_rn(x_lds[slot * NPS + n][k], ws,
                     __fmaf_rn(h_lds[slot * NPS + n][k], wn, acc[n]));
        }
    }

#pragma unroll
    for (int n = 0; n < NPS; ++n) {
        int gn = node0 + slot * NPS + n;
        if (gn < N) {
            float v = acc[n];
            v = (ACT == 0) ? fmaxf(v, 0.0f) : fsigmoid(v);
            out[(size_t)gn * NOUT + j] = v;
        }
    }
}

extern "C" void kernel_launch(void* const* d_in, const int* in_sizes, int n_in,
                              void* d_out, int out_size, void* d_ws, size_t ws_size,
                              hipStream_t stream)
{
    const float* feats    = (const float*)d_in[0];
    const int*   nbr      = (const int*)  d_in[1];
    const float* w_ih1    = (const float*)d_in[2];
    const float* w_hh1    = (const float*)d_in[3];
    const float* b_ih1    = (const float*)d_in[4];
    const float* b_hh1    = (const float*)d_in[5];
    const float* w_self1  = (const float*)d_in[6];
    const float* w_neigh1 = (const float*)d_in[7];
    const float* b1       = (const float*)d_in[8];
    const float* w_ih2    = (const float*)d_in[9];
    const float* w_hh2    = (const float*)d_in[10];
    const float* b_ih2    = (const float*)d_in[11];
    const float* b_hh2    = (const float*)d_in[12];
    const float* w_self2  = (const float*)d_in[13];
    const float* w_neigh2 = (const float*)d_in[14];
    const float* b2       = (const float*)d_in[15];
    float* out = (float*)d_out;

    const int N = in_sizes[0] / IN;   // 50000

    char* ws = (char*)d_ws;
    size_t off = 0;
    auto alloc = [&](size_t bytes) -> void* {
        void* p = (void*)(ws + off);
        off += (bytes + 255) & ~(size_t)255;
        return p;
    };
    uint4* wfrag1    = (uint4*)alloc(16384 * 16);
    uint4* wfrag2    = (uint4*)alloc(16384 * 16);
    float* wT_self1  = (float*)alloc(128 * 128 * 4);
    float* wT_neigh1 = (float*)alloc(128 * 128 * 4);
    float* wT_self2  = (float*)alloc(64 * 128 * 4);
    float* wT_neigh2 = (float*)alloc(64 * 128 * 4);
    float* bsum1     = (float*)alloc(512 * 4);
    float* bsum2     = (float*)alloc(512 * 4);
    float* h_buf     = (float*)alloc((size_t)N * 128 * 4);
    float* out1      = (float*)alloc((size_t)N * 128 * 4);

    // prep
    k_pack_w<<<dim3(64), dim3(256), 0, stream>>>(w_ih1, w_hh1, wfrag1);
    k_pack_w<<<dim3(64), dim3(256), 0, stream>>>(w_ih2, w_hh2, wfrag2);
    k_transpose<<<dim3((128 * 128 + 255) / 256), dim3(256), 0, stream>>>(w_self1, wT_self1, 128, 128);
    k_transpose<<<dim3((128 * 128 + 255) / 256), dim3(256), 0, stream>>>(w_neigh1, wT_neigh1, 128, 128);
    k_transpose<<<dim3((64 * 128 + 255) / 256), dim3(256), 0, stream>>>(w_self2, wT_self2, 64, 128);
    k_transpose<<<dim3((64 * 128 + 255) / 256), dim3(256), 0, stream>>>(w_neigh2, wT_neigh2, 64, 128);
    k_bias_sum<<<dim3(2), dim3(256), 0, stream>>>(b_ih1, b_hh1, bsum1, 512);
    k_bias_sum<<<dim3(2), dim3(256), 0, stream>>>(b_ih2, b_hh2, bsum2, 512);

    const int nblk64 = (N + 63) / 64;
    const int nblk32 = (N + 31) / 32;

    // layer 1
    k_lstm_mfma<<<dim3(nblk64), dim3(256), 0, stream>>>(feats, nbr, wfrag1, bsum1, h_buf, N);
    k_out_linear<128, 0><<<dim3(nblk32), dim3(256), 0, stream>>>(feats, h_buf, wT_self1, wT_neigh1, b1, out1, N);

    // layer 2
    k_lstm_mfma<<<dim3(nblk64), dim3(256), 0, stream>>>(out1, nbr, wfrag2, bsum2, h_buf, N);
    k_out_linear<64, 1><<<dim3(nblk32), dim3(256), 0, stream>>>(out1, h_buf, wT_self2, wT_neigh2, b2, out, N);
}

// Round 4
// 1636.533 us; speedup vs baseline: 4.2690x; 1.0168x over previous
//
#include <hip/hip_runtime.h>
#include <cstdint>
#include <cstddef>

// SAGE-LSTM R4 (= R3 design, compile fix): nontemporal builtin needs a clang
// ext_vector_type, not HIP's uint4 class -> u32x4. Changes vs R2:
// (1) nt gather loads protect the L2-resident 256KB weight slab (R2: 1.85GB
// HBM fetch/dispatch vs 0.43GB ideal = weight refetch), (2) bf16 feature
// buffers (halves gather bytes; bf16 row order == A-frag k-order so staging is
// a straight 16B copy), (3) h_frag kgrp stride 65 (was 64) to spread the
// h-write across 16 banks (R2: 1.2e7 conflict cycles).

constexpr int IN  = 128;
constexpr int DEG = 16;

typedef short bf16x8 __attribute__((ext_vector_type(8)));
typedef float f32x16 __attribute__((ext_vector_type(16)));
typedef unsigned int u32x4 __attribute__((ext_vector_type(4)));

__device__ __forceinline__ float fsigmoid(float x) {
    float e = __expf(-x);
    return __builtin_amdgcn_rcpf(1.0f + e);
}
__device__ __forceinline__ float ftanh(float x) {
    float e = __expf(-2.0f * x);
    return __fmaf_rn(2.0f, __builtin_amdgcn_rcpf(1.0f + e), -1.0f);
}
__device__ __forceinline__ uint32_t pack2bf16(float a, float b) {
    uint32_t ua = __float_as_uint(a) + 0x8000u;   // round-half-up to bf16
    uint32_t ub = __float_as_uint(b) + 0x8000u;
    return (ua >> 16) | (ub & 0xFFFF0000u);
}

// ---------- prep kernels ----------

__global__ void k_transpose(const float* __restrict__ src, float* __restrict__ dst,
                            int R, int C) {
    int i = blockIdx.x * blockDim.x + threadIdx.x;
    if (i < R * C) { int r = i / C, c = i - r * C; dst[c * R + r] = src[i]; }
}

__global__ void k_bias_sum(const float* __restrict__ a, const float* __restrict__ b,
                           float* __restrict__ o, int n) {
    int i = blockIdx.x * blockDim.x + threadIdx.x;
    if (i < n) o[i] = a[i] + b[i];
}

// fp32 -> bf16 cast, 4 elements/thread
__global__ void k_cast_bf16(const float* __restrict__ src, ushort* __restrict__ dst, int n) {
    int i = (blockIdx.x * blockDim.x + threadIdx.x) * 4;
    if (i + 3 < n) {
        float4 v = *(const float4*)(src + i);
        uint2 d; d.x = pack2bf16(v.x, v.y); d.y = pack2bf16(v.z, v.w);
        *(uint2*)(dst + i) = d;
    } else {
        for (int k = i; k < n; ++k)
            dst[k] = (ushort)((__float_as_uint(src[k]) + 0x8000u) >> 16);
    }
}

// Pack W = [W_ih^T ; W_hh^T] (256 x 512 logical, k-major) into MFMA B-fragment
// order: flat tid = ((kst*16 + tile)*64 + lane); B[k][n]: n = tile*32+(lane&31),
// k = kst*16 + (lane>>5)*8 + j.
__global__ void k_pack_w(const float* __restrict__ w_ih, const float* __restrict__ w_hh,
                         u32x4* __restrict__ wfrag) {
    int tid  = blockIdx.x * 256 + threadIdx.x;   // 0..16383
    int lane = tid & 63;
    int tile = (tid >> 6) & 15;
    int kst  = tid >> 10;
    int n     = tile * 32 + (lane & 31);
    int kbase = kst * 16 + (lane >> 5) * 8;
    float v[8];
#pragma unroll
    for (int j = 0; j < 8; ++j) {
        int k = kbase + j;
        v[j] = (k < 128) ? w_ih[n * 128 + k] : w_hh[n * 128 + (k - 128)];
    }
    u32x4 d;
    d.x = pack2bf16(v[0], v[1]);
    d.y = pack2bf16(v[2], v[3]);
    d.z = pack2bf16(v[4], v[5]);
    d.w = pack2bf16(v[6], v[7]);
    wfrag[tid] = d;
}

// ---------- LSTM aggregator (MFMA) ----------

__global__ __launch_bounds__(256, 2) void k_lstm_mfma(
    const ushort* __restrict__ feats,  // [N,128] bf16 gather source
    const int*    __restrict__ nbr,    // [N,16]
    const u32x4*  __restrict__ wfrag,  // packed B-frags, 16384 * 16B
    const float*  __restrict__ bsum,   // [512] b_ih+b_hh
    ushort*       __restrict__ h_out,  // [N,128] bf16
    int N)
{
    __shared__ u32x4 x_frag[16 * 64];   // [kgrp][m] bf16 A-layout, 16KB
    __shared__ u32x4 h_frag[16 * 65];   // padded stride 65 (h-write bank spread)
    __shared__ int   idxs[DEG * 64];    // [t][m]

    const int tid   = threadIdx.x;
    const int lane  = tid & 63;
    const int w     = tid >> 6;         // wave 0..3
    const int mrow  = lane & 31;
    const int khalf = lane >> 5;
    const int node0 = blockIdx.x * 64;

    for (int i = tid; i < 64 * DEG; i += 256) {
        int m = i >> 4, t = i & 15;
        int gn = node0 + m; if (gn >= N) gn = N - 1;
        idxs[t * 64 + m] = nbr[gn * DEG + t];
    }
    for (int i = tid; i < 16 * 65; i += 256) h_frag[i] = u32x4{0u, 0u, 0u, 0u};

    float binit[4];
#pragma unroll
    for (int g = 0; g < 4; ++g) binit[g] = bsum[g * 128 + w * 32 + (lane & 31)];

    f32x16 acc[2][4];
    float  cst[2][16];
#pragma unroll
    for (int Mt = 0; Mt < 2; ++Mt)
#pragma unroll
        for (int r = 0; r < 16; ++r) {
            cst[Mt][r] = 0.0f;
#pragma unroll
            for (int g = 0; g < 4; ++g) acc[Mt][g][r] = binit[g];
        }

    const u32x4* wbase = wfrag + (w * 64 + lane);   // + kst*1024 + g*256

    __syncthreads();

    const int m_st  = tid >> 2;   // staging: my node row (0..63)
    const int c4_st = tid & 3;    // staging: my uint4 phase

    for (int t = 0; t < DEG; ++t) {
        // ---- stage x_t: bf16 row -> A-frag layout, straight 16B copies.
        // 4 lanes/row; each instr a 4-lane quad reads 64B contiguous. nt =
        // don't evict the L2-resident weights.
        {
            const u32x4* src = (const u32x4*)(feats + (size_t)idxs[t * 64 + m_st] * IN);
#pragma unroll
            for (int i = 0; i < 4; ++i) {
                int f16 = i * 4 + c4_st;             // uint4 idx 0..15 (k = f16*8..+7)
                x_frag[f16 * 64 + m_st] = __builtin_nontemporal_load(src + f16);
            }
        }
        __syncthreads();   // x_frag(t) + h_frag(t-1) ready

        // ---- K-loop: 16 k-steps x (2 M-tiles x 4 gate-tiles) MFMA
#pragma unroll
        for (int kst = 0; kst < 16; ++kst) {
            const u32x4* asrc = (kst < 8) ? &x_frag[(kst * 2 + khalf) * 64]
                                          : &h_frag[((kst - 8) * 2 + khalf) * 65];
            bf16x8 a0 = __builtin_bit_cast(bf16x8, asrc[mrow]);
            bf16x8 a1 = __builtin_bit_cast(bf16x8, asrc[32 + mrow]);
#pragma unroll
            for (int g = 0; g < 4; ++g) {
                bf16x8 b = __builtin_bit_cast(bf16x8, wbase[kst * 1024 + g * 256]);
                acc[0][g] = __builtin_amdgcn_mfma_f32_32x32x16_bf16(a0, b, acc[0][g], 0, 0, 0);
                acc[1][g] = __builtin_amdgcn_mfma_f32_32x32x16_bf16(a1, b, acc[1][g], 0, 0, 0);
            }
        }
        __syncthreads();   // all waves done reading x_frag/h_frag

        // ---- LSTM cell update (lane-local i/f/g/o), write h(t) to h_frag
#pragma unroll
        for (int Mt = 0; Mt < 2; ++Mt) {
#pragma unroll
            for (int r = 0; r < 16; ++r) {
                float gi = acc[Mt][0][r], gf = acc[Mt][1][r];
                float gg = acc[Mt][2][r], go = acc[Mt][3][r];
                acc[Mt][0][r] = binit[0];  acc[Mt][1][r] = binit[1];
                acc[Mt][2][r] = binit[2];  acc[Mt][3][r] = binit[3];
                float iv = fsigmoid(gi);
                float fv = fsigmoid(gf);
                float gv = ftanh(gg);
                float ov = fsigmoid(go);
                float cv = __fmaf_rn(fv, cst[Mt][r], iv * gv);
                cst[Mt][r] = cv;
                float hv = ov * ftanh(cv);
                // pack (j even, j odd) via lane^1 exchange; even lane writes b32
                uint32_t hb = __float_as_uint(hv) + 0x8000u;
                uint32_t pb = (uint32_t)__shfl_xor((int)hb, 1, 64);
                if ((lane & 1) == 0) {
                    int row = Mt * 32 + (r & 3) + 8 * (r >> 2) + 4 * khalf;
                    int j   = w * 32 + (lane & 31);
                    ((uint32_t*)h_frag)[((j >> 3) * 65 + row) * 4 + ((lane >> 1) & 3)] =
                        (hb >> 16) | (pb & 0xFFFF0000u);
                }
            }
        }
    }

    __syncthreads();
    // final h: bf16 A-layout -> coalesced bf16 row store
    for (int i = tid; i < 64 * IN; i += 256) {
        int m = i >> 7, j = i & 127;
        int gn = node0 + m;
        if (gn < N)
            h_out[(size_t)gn * IN + j] =
                ((const ushort*)h_frag)[((j >> 3) * 65 + m) * 8 + (j & 7)];
    }
}

// ---------- output linear (fp32 math, bf16 inputs) ----------

template <int NOUT, int ACT, typename OutT>
__global__ __launch_bounds__(256) void k_out_linear(
    const ushort* __restrict__ x, const ushort* __restrict__ h,
    const float* __restrict__ wTs, const float* __restrict__ wTn,
    const float* __restrict__ bias, OutT* __restrict__ out, int N)
{
    constexpr int SLOTS = 256 / NOUT;
    constexpr int NPS   = 32 / SLOTS;
    __shared__ alignas(16) float x_lds[32][IN];
    __shared__ alignas(16) float h_lds[32][IN];

    const int tid  = threadIdx.x;
    const int j    = tid % NOUT;
    const int slot = tid / NOUT;
    const int node0 = blockIdx.x * 32;

    for (int i = tid; i < 32 * (IN / 8); i += 256) {   // 32 rows x 16 x 8-elem
        int n = i >> 4, u4 = i & 15;
        int gn = node0 + n; if (gn >= N) gn = N - 1;
        u32x4 xv = *(const u32x4*)(x + (size_t)gn * IN + u4 * 8);
        u32x4 hv = *(const u32x4*)(h + (size_t)gn * IN + u4 * 8);
        float* xd = &x_lds[n][u4 * 8];
        float* hd = &h_lds[n][u4 * 8];
        xd[0] = __uint_as_float(xv.x << 16); xd[1] = __uint_as_float(xv.x & 0xFFFF0000u);
        xd[2] = __uint_as_float(xv.y << 16); xd[3] = __uint_as_float(xv.y & 0xFFFF0000u);
        xd[4] = __uint_as_float(xv.z << 16); xd[5] = __uint_as_float(xv.z & 0xFFFF0000u);
        xd[6] = __uint_as_float(xv.w << 16); xd[7] = __uint_as_float(xv.w & 0xFFFF0000u);
        hd[0] = __uint_as_float(hv.x << 16); hd[1] = __uint_as_float(hv.x & 0xFFFF0000u);
        hd[2] = __uint_as_float(hv.y << 16); hd[3] = __uint_as_float(hv.y & 0xFFFF0000u);
        hd[4] = __uint_as_float(hv.z << 16); hd[5] = __uint_as_float(hv.z & 0xFFFF0000u);
        hd[6] = __uint_as_float(hv.w << 16); hd[7] = __uint_as_float(hv.w & 0xFFFF0000u);
    }
    __syncthreads();

    float acc[NPS];
    const float bj = bias[j];
#pragma unroll
    for (int n = 0; n < NPS; ++n) acc[n] = bj;

#pragma unroll 2
    for (int k = 0; k < IN; ++k) {
        const float ws = wTs[k * NOUT + j];
        const float wn = wTn[k * NOUT + j];
#pragma unroll
        for (int n = 0; n < NPS; ++n) {
            acc[n] = __fmaf_rn(x_lds[slot * NPS + n][k], ws,
                     __fmaf_rn(h_lds[slot * NPS + n][k], wn, acc[n]));
        }
    }

#pragma unroll
    for (int n = 0; n < NPS; ++n) {
        int gn = node0 + slot * NPS + n;
        if (gn < N) {
            float v = acc[n];
            v = (ACT == 0) ? fmaxf(v, 0.0f) : fsigmoid(v);
            if constexpr (sizeof(OutT) == 2)
                out[(size_t)gn * NOUT + j] = (OutT)((__float_as_uint(v) + 0x8000u) >> 16);
            else
                out[(size_t)gn * NOUT + j] = v;
        }
    }
}

extern "C" void kernel_launch(void* const* d_in, const int* in_sizes, int n_in,
                              void* d_out, int out_size, void* d_ws, size_t ws_size,
                              hipStream_t stream)
{
    const float* feats    = (const float*)d_in[0];
    const int*   nbr      = (const int*)  d_in[1];
    const float* w_ih1    = (const float*)d_in[2];
    const float* w_hh1    = (const float*)d_in[3];
    const float* b_ih1    = (const float*)d_in[4];
    const float* b_hh1    = (const float*)d_in[5];
    const float* w_self1  = (const float*)d_in[6];
    const float* w_neigh1 = (const float*)d_in[7];
    const float* b1       = (const float*)d_in[8];
    const float* w_ih2    = (const float*)d_in[9];
    const float* w_hh2    = (const float*)d_in[10];
    const float* b_ih2    = (const float*)d_in[11];
    const float* b_hh2    = (const float*)d_in[12];
    const float* w_self2  = (const float*)d_in[13];
    const float* w_neigh2 = (const float*)d_in[14];
    const float* b2       = (const float*)d_in[15];
    float* out = (float*)d_out;

    const int N = in_sizes[0] / IN;   // 50000

    char* ws = (char*)d_ws;
    size_t off = 0;
    auto alloc = [&](size_t bytes) -> void* {
        void* p = (void*)(ws + off);
        off += (bytes + 255) & ~(size_t)255;
        return p;
    };
    u32x4*  wfrag1    = (u32x4*)alloc(16384 * 16);
    u32x4*  wfrag2    = (u32x4*)alloc(16384 * 16);
    float*  wT_self1  = (float*)alloc(128 * 128 * 4);
    float*  wT_neigh1 = (float*)alloc(128 * 128 * 4);
    float*  wT_self2  = (float*)alloc(64 * 128 * 4);
    float*  wT_neigh2 = (float*)alloc(64 * 128 * 4);
    float*  bsum1     = (float*)alloc(512 * 4);
    float*  bsum2     = (float*)alloc(512 * 4);
    ushort* feats_bf  = (ushort*)alloc((size_t)N * 128 * 2);
    ushort* h_buf     = (ushort*)alloc((size_t)N * 128 * 2);
    ushort* out1      = (ushort*)alloc((size_t)N * 128 * 2);

    // prep
    k_pack_w<<<dim3(64), dim3(256), 0, stream>>>(w_ih1, w_hh1, wfrag1);
    k_pack_w<<<dim3(64), dim3(256), 0, stream>>>(w_ih2, w_hh2, wfrag2);
    k_transpose<<<dim3((128 * 128 + 255) / 256), dim3(256), 0, stream>>>(w_self1, wT_self1, 128, 128);
    k_transpose<<<dim3((128 * 128 + 255) / 256), dim3(256), 0, stream>>>(w_neigh1, wT_neigh1, 128, 128);
    k_transpose<<<dim3((64 * 128 + 255) / 256), dim3(256), 0, stream>>>(w_self2, wT_self2, 64, 128);
    k_transpose<<<dim3((64 * 128 + 255) / 256), dim3(256), 0, stream>>>(w_neigh2, wT_neigh2, 64, 128);
    k_bias_sum<<<dim3(2), dim3(256), 0, stream>>>(b_ih1, b_hh1, bsum1, 512);
    k_bias_sum<<<dim3(2), dim3(256), 0, stream>>>(b_ih2, b_hh2, bsum2, 512);
    k_cast_bf16<<<dim3((N * 128 / 4 + 255) / 256), dim3(256), 0, stream>>>(feats, feats_bf, N * 128);

    const int nblk64 = (N + 63) / 64;
    const int nblk32 = (N + 31) / 32;

    // layer 1
    k_lstm_mfma<<<dim3(nblk64), dim3(256), 0, stream>>>(feats_bf, nbr, wfrag1, bsum1, h_buf, N);
    k_out_linear<128, 0, ushort><<<dim3(nblk32), dim3(256), 0, stream>>>(feats_bf, h_buf, wT_self1, wT_neigh1, b1, out1, N);

    // layer 2
    k_lstm_mfma<<<dim3(nblk64), dim3(256), 0, stream>>>(out1, nbr, wfrag2, bsum2, h_buf, N);
    k_out_linear<64, 1, float><<<dim3(nblk32), dim3(256), 0, stream>>>(out1, h_buf, wT_self2, wT_neigh2, b2, out, N);
}